// Round 1
// baseline (111.386 us; speedup 1.0000x reference)
//
#include <hip/hip_runtime.h>
#include <math.h>

// Problem constants (fixed shapes from setup_inputs)
#define B_    8
#define C_    4
#define H_    256
#define W_    256
#define NCLS  3                      // classes 1..3
#define NROWS (NCLS * B_ * H_)       // 6144 rows for horizontal pass
#define NBLK  (NROWS / 4)            // 1536 horiz blocks (4 rows/block)
#define BIGVAL (1 << 26)             // pad value, never wins the min

// ---------------------------------------------------------------------------
// Kernel 1: vertical 1D distance g = min(d_up, d_down, 512) via bitmask scan.
// Block = (class, b, w-tile of 64). 4 waves = 4 h-chunks of 64 rows.
// Thread (hc, lane): fully-unrolled 64 coalesced row loads into registers
// (max memory-level parallelism), builds u64 bg bitmask, then per row derives
// d_up via clz on prefix bits and d_down via ctz on suffix bits; cross-chunk
// carries via 4-entry LDS summaries. Matches ref semantics: no-bg-above =>
// d_up = h+512 (clamped 512); g = min(du, dd, BIG=512).
// Also zeroes the horiz completion counter (ws is re-poisoned each iter).
// ---------------------------------------------------------------------------
__global__ __launch_bounds__(256) void vert_g_kernel(const int* __restrict__ mask,
                                                     unsigned short* __restrict__ gbuf,
                                                     int* __restrict__ cnt) {
    if (blockIdx.x == 0 && threadIdx.x == 0) *cnt = 0;   // stream-order visible to horiz

    const int lane = threadIdx.x & 63;
    const int hc   = threadIdx.x >> 6;          // h-chunk 0..3
    const int blk  = blockIdx.x;                // 0..95
    const int wt   = blk & 3;
    const int b    = (blk >> 2) & 7;
    const int c_i  = blk >> 5;                  // 0..2
    const int cls  = c_i + 1;
    const int w    = (wt << 6) + lane;

    __shared__ int last_sh[4][64];              // highest bg row per chunk (or -512)
    __shared__ int first_sh[4][64];             // lowest bg row per chunk (or big)

    const int* mptr = mask + (b << 16) + (hc << 14) + w;   // row hc*64, col w
    int m[64];
    #pragma unroll
    for (int i = 0; i < 64; ++i) m[i] = mptr[i << 8];      // all independent
    unsigned long long bg = 0ull;
    #pragma unroll
    for (int i = 0; i < 64; ++i)
        bg |= (unsigned long long)(m[i] != cls) << i;

    last_sh[hc][lane]  = bg ? ((hc << 6) + 63 - __builtin_clzll(bg)) : -512;
    first_sh[hc][lane] = bg ? ((hc << 6) + __builtin_ctzll(bg)) : (1 << 20);
    __syncthreads();

    int carry_up = -512;                        // last bg row in chunks above
    #pragma unroll
    for (int k = 0; k < 4; ++k)
        if (k < hc) carry_up = max(carry_up, last_sh[k][lane]);
    int carry_dn = 1 << 20;                     // first bg row in chunks below
    #pragma unroll
    for (int k = 0; k < 4; ++k)
        if (k > hc) carry_dn = min(carry_dn, first_sh[k][lane]);

    unsigned short* gout = gbuf + (((c_i << 3) + b) << 16) + (hc << 14) + w;
    #pragma unroll 4
    for (int i = 0; i < 64; ++i) {
        int h = (hc << 6) + i;
        unsigned long long le = bg & (~0ull >> (63 - i));   // bg bits at rows <= h
        int last = le ? ((hc << 6) + 63 - __builtin_clzll(le)) : carry_up;
        int du = h - last;
        unsigned long long ge = bg >> i;                    // bg bits at rows >= h
        int first = ge ? (h + __builtin_ctzll(ge)) : carry_dn;
        int dd = first - h;
        int g = min(min(du, dd), 512);
        gout[i << 8] = (unsigned short)g;
    }
}

// ---------------------------------------------------------------------------
// Kernel 2: exact horizontal lower-envelope + fused loss partial + FUSED
// deterministic final reduction (replaces the former 1-block final kernel).
// 1536 blocks x 4 waves, ONE row per wave. The per-row phase has no
// __syncthreads (single-wave LDS slice ownership); one barrier at the end
// for the block partial. Each block release-stores its fp64 partial and
// acq_rel-increments a device-scope counter; the LAST block reduces all
// 1536 partials in FIXED index order -> bitwise-deterministic output.
// Exactness of the window search: D2[x] <= g2[x]; an x' improves only if
// |x-x'| <= g[x]-1 <= rowmax(g)-1 = R, so radius-R search is exact.
// ---------------------------------------------------------------------------
__global__ __launch_bounds__(256) void horiz_kernel(const unsigned short* __restrict__ gbuf,
                                                    const float* __restrict__ pred,
                                                    double* __restrict__ acc,
                                                    int* __restrict__ cnt,
                                                    float* __restrict__ out) {
    const int lane = threadIdx.x & 63;
    const int wv   = threadIdx.x >> 6;
    const int row  = blockIdx.x * 4 + wv;       // 0..6143
    const int c_i  = row >> 11;
    const int b    = (row >> 8) & 7;
    const int h    = row & 255;
    const int cls  = c_i + 1;

    __shared__ __align__(16) int ext[4][512];   // per-wave padded g2 row: x = i-128
    __shared__ double wpart[4];
    __shared__ double fsum[4];
    __shared__ int lastflag;

    const int x0 = lane << 2;
    // issue both independent global loads immediately (overlapped latencies)
    const float* prow = pred + ((((b << 2) + cls) << 8) + h) * 256;
    float4 pv = *(const float4*)(prow + x0);
    ushort4 gv = *(const ushort4*)(gbuf + row * 256 + x0);

    int g0 = gv.x, g1 = gv.y, g2v = gv.z, g3 = gv.w;
    int q0 = g0 * g0, q1 = g1 * g1, q2 = g2v * g2v, q3 = g3 * g3;
    *(int4*)&ext[wv][128 + x0] = make_int4(q0, q1, q2, q3);
    // pads: [0,128) and [384,512)
    ext[wv][lane]       = BIGVAL;
    ext[wv][64 + lane]  = BIGVAL;
    ext[wv][384 + lane] = BIGVAL;
    ext[wv][448 + lane] = BIGVAL;
    // no barrier: single-wave ownership of ext[wv]; lgkmcnt orders ds ops

    // wave max of g -> window radius
    int gm = max(max(g0, g1), max(g2v, g3));
    #pragma unroll
    for (int off = 32; off > 0; off >>= 1) gm = max(gm, __shfl_xor(gm, off, 64));
    const int R = gm - 1;

    int D2[4] = { q0, q1, q2, q3 };
    const int* e = &ext[wv][128];

    if (R >= 120) {
        // brute force over all source columns (rare)
        for (int xp = 0; xp < 256; ++xp) {
            int s = e[xp];
            #pragma unroll
            for (int j = 0; j < 4; ++j) {
                int d = (x0 + j) - xp;
                int cand = s + d * d;
                D2[j] = (cand < D2[j]) ? cand : D2[j];
            }
        }
    } else if (R >= 1) {
        for (int o = 1; o <= R; ++o) {
            int oo = o * o;
            #pragma unroll
            for (int j = 0; j < 4; ++j) {
                int xj = x0 + j;
                int c1 = e[xj + o];
                int c2 = e[xj - o];
                int cm = (c1 < c2) ? c1 : c2;
                int cand = cm + oo;
                D2[j] = (cand < D2[j]) ? cand : D2[j];
            }
        }
    }
    // (R <= 0: all background in window -> D2 = g2)

    // loss terms: f32 sqrt (D2 < 2^24, exact in f32), fp64 accumulate
    double sum = (double)(sqrtf((float)D2[0]) * pv.x)
               + (double)(sqrtf((float)D2[1]) * pv.y)
               + (double)(sqrtf((float)D2[2]) * pv.z)
               + (double)(sqrtf((float)D2[3]) * pv.w);
    #pragma unroll
    for (int off = 32; off > 0; off >>= 1) sum += __shfl_xor(sum, off, 64);
    if (lane == 0) wpart[wv] = sum;
    __syncthreads();

    // block partial -> global, then last-block detection
    if (threadIdx.x == 0) {
        double bsum = (wpart[0] + wpart[1]) + (wpart[2] + wpart[3]);
        __hip_atomic_store(&acc[blockIdx.x], bsum, __ATOMIC_RELEASE,
                           __HIP_MEMORY_SCOPE_AGENT);
        int old = __hip_atomic_fetch_add(cnt, 1, __ATOMIC_ACQ_REL,
                                         __HIP_MEMORY_SCOPE_AGENT);
        lastflag = (old == NBLK - 1) ? 1 : 0;
    }
    __syncthreads();
    if (!lastflag) return;

    // last block: deterministic final reduce over fixed index order
    const int t = threadIdx.x;
    double s = 0.0;
    #pragma unroll
    for (int i = 0; i < NBLK / 256; ++i)
        s += __hip_atomic_load(&acc[t + i * 256], __ATOMIC_RELAXED,
                               __HIP_MEMORY_SCOPE_AGENT);
    #pragma unroll
    for (int off = 32; off > 0; off >>= 1) s += __shfl_xor(s, off, 64);
    if ((t & 63) == 0) fsum[t >> 6] = s;
    __syncthreads();
    if (t == 0) {
        double total = (fsum[0] + fsum[1]) + (fsum[2] + fsum[3]);
        double nd = sqrt(131072.0) + 1e-6;          // sqrt(H^2+W^2)+1e-6
        double norm = (double)(float)nd;            // ref casts to float32
        out[0] = (float)(total / norm / ((double)NCLS * (double)(B_ * H_ * W_)));
    }
}

extern "C" void kernel_launch(void* const* d_in, const int* in_sizes, int n_in,
                              void* d_out, int out_size, void* d_ws, size_t ws_size,
                              hipStream_t stream) {
    const float* pred = (const float*)d_in[0];   // [8,4,256,256] f32
    const int*   mask = (const int*)d_in[1];     // [8,256,256] int
    float* out = (float*)d_out;

    char* ws = (char*)d_ws;
    double* acc = (double*)ws;                                   // 1536 doubles
    int* cnt = (int*)(ws + 16384);                               // completion counter
    unsigned short* gbuf = (unsigned short*)(ws + 65536);        // 3 MB

    vert_g_kernel<<<NCLS * 8 * 4, 256, 0, stream>>>(mask, gbuf, cnt);
    horiz_kernel<<<NROWS / 4, 256, 0, stream>>>(gbuf, pred, acc, cnt, out);
}

// Round 2
// 83.135 us; speedup vs baseline: 1.3398x; 1.3398x over previous
//
#include <hip/hip_runtime.h>
#include <math.h>

// Problem constants (fixed shapes from setup_inputs)
#define B_    8
#define C_    4
#define H_    256
#define W_    256
#define NCLS  3                      // classes 1..3
#define NROWS (NCLS * B_ * H_)       // 6144 rows for horizontal pass
#define NBLK  (NROWS / 4)            // 1536 horiz blocks (4 rows/block)
#define BIGVAL (1 << 26)             // pad value, never wins the min

// ---------------------------------------------------------------------------
// Kernel 1: vertical 1D distance g = min(d_up, d_down, 512) via bitmask scan.
// Block = (class, b, w-tile of 64). 4 waves = 4 h-chunks of 64 rows.
// Thread (hc, lane): fully-unrolled 64 coalesced row loads into registers
// (max memory-level parallelism), builds u64 bg bitmask, then per row derives
// d_up via clz on prefix bits and d_down via ctz on suffix bits; cross-chunk
// carries via 4-entry LDS summaries. Matches ref semantics: no-bg-above =>
// d_up = h+512 (clamped 512); g = min(du, dd, BIG=512).
// Also zeroes the horiz completion counter (ws is re-poisoned each iter);
// visibility to horiz is via the runtime's end-of-kernel L2 writeback.
// ---------------------------------------------------------------------------
__global__ __launch_bounds__(256) void vert_g_kernel(const int* __restrict__ mask,
                                                     unsigned short* __restrict__ gbuf,
                                                     int* __restrict__ cnt) {
    if (blockIdx.x == 0 && threadIdx.x == 0) *cnt = 0;   // stream-order visible to horiz

    const int lane = threadIdx.x & 63;
    const int hc   = threadIdx.x >> 6;          // h-chunk 0..3
    const int blk  = blockIdx.x;                // 0..95
    const int wt   = blk & 3;
    const int b    = (blk >> 2) & 7;
    const int c_i  = blk >> 5;                  // 0..2
    const int cls  = c_i + 1;
    const int w    = (wt << 6) + lane;

    __shared__ int last_sh[4][64];              // highest bg row per chunk (or -512)
    __shared__ int first_sh[4][64];             // lowest bg row per chunk (or big)

    const int* mptr = mask + (b << 16) + (hc << 14) + w;   // row hc*64, col w
    int m[64];
    #pragma unroll
    for (int i = 0; i < 64; ++i) m[i] = mptr[i << 8];      // all independent
    unsigned long long bg = 0ull;
    #pragma unroll
    for (int i = 0; i < 64; ++i)
        bg |= (unsigned long long)(m[i] != cls) << i;

    last_sh[hc][lane]  = bg ? ((hc << 6) + 63 - __builtin_clzll(bg)) : -512;
    first_sh[hc][lane] = bg ? ((hc << 6) + __builtin_ctzll(bg)) : (1 << 20);
    __syncthreads();

    int carry_up = -512;                        // last bg row in chunks above
    #pragma unroll
    for (int k = 0; k < 4; ++k)
        if (k < hc) carry_up = max(carry_up, last_sh[k][lane]);
    int carry_dn = 1 << 20;                     // first bg row in chunks below
    #pragma unroll
    for (int k = 0; k < 4; ++k)
        if (k > hc) carry_dn = min(carry_dn, first_sh[k][lane]);

    unsigned short* gout = gbuf + (((c_i << 3) + b) << 16) + (hc << 14) + w;
    #pragma unroll 4
    for (int i = 0; i < 64; ++i) {
        int h = (hc << 6) + i;
        unsigned long long le = bg & (~0ull >> (63 - i));   // bg bits at rows <= h
        int last = le ? ((hc << 6) + 63 - __builtin_clzll(le)) : carry_up;
        int du = h - last;
        unsigned long long ge = bg >> i;                    // bg bits at rows >= h
        int first = ge ? (h + __builtin_ctzll(ge)) : carry_dn;
        int dd = first - h;
        int g = min(min(du, dd), 512);
        gout[i << 8] = (unsigned short)g;
    }
}

// ---------------------------------------------------------------------------
// Kernel 2: exact horizontal lower-envelope + fused loss partial + fused
// deterministic final reduction. 1536 blocks x 4 waves, ONE row per wave.
// Last-block sync uses ONLY relaxed agent-scope atomics (sc1 ops that bypass
// the non-coherent per-XCD L2 straight to the coherence point) + a manual
// `s_waitcnt vmcnt(0)` between the partial store and the counter RMW.
// Rationale: acquire/release at agent scope on gfx950 emit buffer_wbl2 /
// buffer_inv (FULL per-XCD L2 writeback/invalidate) per block — 1536 of
// those cost ~45us (measured last round). Relaxed+vmcnt gives the same
// happens-before on this HW with zero cache maintenance.
// Determinism: last block sums the 1536 partials in fixed index order.
// Exactness of the window search: D2[x] <= g2[x]; an x' improves only if
// |x-x'| <= g[x]-1 <= rowmax(g)-1 = R, so radius-R search is exact.
// ---------------------------------------------------------------------------
__global__ __launch_bounds__(256) void horiz_kernel(const unsigned short* __restrict__ gbuf,
                                                    const float* __restrict__ pred,
                                                    double* __restrict__ acc,
                                                    int* __restrict__ cnt,
                                                    float* __restrict__ out) {
    const int lane = threadIdx.x & 63;
    const int wv   = threadIdx.x >> 6;
    const int row  = blockIdx.x * 4 + wv;       // 0..6143
    const int c_i  = row >> 11;
    const int b    = (row >> 8) & 7;
    const int h    = row & 255;
    const int cls  = c_i + 1;

    __shared__ __align__(16) int ext[4][512];   // per-wave padded g2 row: x = i-128
    __shared__ double wpart[4];
    __shared__ double fsum[4];
    __shared__ int lastflag;

    const int x0 = lane << 2;
    // issue both independent global loads immediately (overlapped latencies)
    const float* prow = pred + ((((b << 2) + cls) << 8) + h) * 256;
    float4 pv = *(const float4*)(prow + x0);
    ushort4 gv = *(const ushort4*)(gbuf + row * 256 + x0);

    int g0 = gv.x, g1 = gv.y, g2v = gv.z, g3 = gv.w;
    int q0 = g0 * g0, q1 = g1 * g1, q2 = g2v * g2v, q3 = g3 * g3;
    *(int4*)&ext[wv][128 + x0] = make_int4(q0, q1, q2, q3);
    // pads: [0,128) and [384,512)
    ext[wv][lane]       = BIGVAL;
    ext[wv][64 + lane]  = BIGVAL;
    ext[wv][384 + lane] = BIGVAL;
    ext[wv][448 + lane] = BIGVAL;
    // no barrier: single-wave ownership of ext[wv]; lgkmcnt orders ds ops

    // wave max of g -> window radius
    int gm = max(max(g0, g1), max(g2v, g3));
    #pragma unroll
    for (int off = 32; off > 0; off >>= 1) gm = max(gm, __shfl_xor(gm, off, 64));
    const int R = gm - 1;

    int D2[4] = { q0, q1, q2, q3 };
    const int* e = &ext[wv][128];

    if (R >= 120) {
        // brute force over all source columns (rare)
        for (int xp = 0; xp < 256; ++xp) {
            int s = e[xp];
            #pragma unroll
            for (int j = 0; j < 4; ++j) {
                int d = (x0 + j) - xp;
                int cand = s + d * d;
                D2[j] = (cand < D2[j]) ? cand : D2[j];
            }
        }
    } else if (R >= 1) {
        for (int o = 1; o <= R; ++o) {
            int oo = o * o;
            #pragma unroll
            for (int j = 0; j < 4; ++j) {
                int xj = x0 + j;
                int c1 = e[xj + o];
                int c2 = e[xj - o];
                int cm = (c1 < c2) ? c1 : c2;
                int cand = cm + oo;
                D2[j] = (cand < D2[j]) ? cand : D2[j];
            }
        }
    }
    // (R <= 0: all background in window -> D2 = g2)

    // loss terms: f32 sqrt (D2 < 2^24, exact in f32), fp64 accumulate
    double sum = (double)(sqrtf((float)D2[0]) * pv.x)
               + (double)(sqrtf((float)D2[1]) * pv.y)
               + (double)(sqrtf((float)D2[2]) * pv.z)
               + (double)(sqrtf((float)D2[3]) * pv.w);
    #pragma unroll
    for (int off = 32; off > 0; off >>= 1) sum += __shfl_xor(sum, off, 64);
    if (lane == 0) wpart[wv] = sum;
    __syncthreads();

    // block partial -> global (relaxed sc1, bypasses non-coherent caches),
    // manual vmcnt drain, then relaxed counter RMW (no cache maintenance).
    if (threadIdx.x == 0) {
        double bsum = (wpart[0] + wpart[1]) + (wpart[2] + wpart[3]);
        __hip_atomic_store(&acc[blockIdx.x], bsum, __ATOMIC_RELAXED,
                           __HIP_MEMORY_SCOPE_AGENT);
        asm volatile("s_waitcnt vmcnt(0)" ::: "memory");  // store at coherence point
        int old = __hip_atomic_fetch_add(cnt, 1, __ATOMIC_RELAXED,
                                         __HIP_MEMORY_SCOPE_AGENT);
        lastflag = (old == NBLK - 1) ? 1 : 0;
    }
    __syncthreads();
    if (!lastflag) return;

    // last block: deterministic final reduce over fixed index order.
    // Relaxed agent-scope loads read from the coherence point (cannot hit
    // stale L1/L2); all 1536 partials are there per the vmcnt+RMW protocol.
    const int t = threadIdx.x;
    double s = 0.0;
    #pragma unroll
    for (int i = 0; i < NBLK / 256; ++i)
        s += __hip_atomic_load(&acc[t + i * 256], __ATOMIC_RELAXED,
                               __HIP_MEMORY_SCOPE_AGENT);
    #pragma unroll
    for (int off = 32; off > 0; off >>= 1) s += __shfl_xor(s, off, 64);
    if ((t & 63) == 0) fsum[t >> 6] = s;
    __syncthreads();
    if (t == 0) {
        double total = (fsum[0] + fsum[1]) + (fsum[2] + fsum[3]);
        double nd = sqrt(131072.0) + 1e-6;          // sqrt(H^2+W^2)+1e-6
        double norm = (double)(float)nd;            // ref casts to float32
        out[0] = (float)(total / norm / ((double)NCLS * (double)(B_ * H_ * W_)));
    }
}

extern "C" void kernel_launch(void* const* d_in, const int* in_sizes, int n_in,
                              void* d_out, int out_size, void* d_ws, size_t ws_size,
                              hipStream_t stream) {
    const float* pred = (const float*)d_in[0];   // [8,4,256,256] f32
    const int*   mask = (const int*)d_in[1];     // [8,256,256] int
    float* out = (float*)d_out;

    char* ws = (char*)d_ws;
    double* acc = (double*)ws;                                   // 1536 doubles
    int* cnt = (int*)(ws + 16384);                               // completion counter
    unsigned short* gbuf = (unsigned short*)(ws + 65536);        // 3 MB

    vert_g_kernel<<<NCLS * 8 * 4, 256, 0, stream>>>(mask, gbuf, cnt);
    horiz_kernel<<<NROWS / 4, 256, 0, stream>>>(gbuf, pred, acc, cnt, out);
}

// Round 3
// 68.157 us; speedup vs baseline: 1.6342x; 1.2197x over previous
//
#include <hip/hip_runtime.h>
#include <math.h>

// Problem constants (fixed shapes from setup_inputs)
#define B_    8
#define C_    4
#define H_    256
#define W_    256
#define NCLS  3                      // classes 1..3
#define NROWS (NCLS * B_ * H_)       // 6144 rows for horizontal pass
#define NBLK  (NROWS / 4)            // 1536 horiz blocks (4 rows/block)
#define NLINES 64                    // first-level counters (1536 = 64 x 24)
#define LINE_DEPTH (NBLK / NLINES)   // 24 blocks per line
#define CNT_STRIDE 32                // ints between counters (128 B, own line)
#define BIGVAL (1 << 26)             // pad value, never wins the min

// ---------------------------------------------------------------------------
// Kernel 1: vertical 1D distance g = min(d_up, d_down, 512) via bitmask scan.
// Block = (class, b, w-tile of 64). 4 waves = 4 h-chunks of 64 rows.
// Thread (hc, lane): fully-unrolled 64 coalesced row loads into registers
// (max memory-level parallelism), builds u64 bg bitmask, then per row derives
// d_up via clz on prefix bits and d_down via ctz on suffix bits; cross-chunk
// carries via 4-entry LDS summaries. Matches ref semantics: no-bg-above =>
// d_up = h+512 (clamped 512); g = min(du, dd, BIG=512).
// Also zeroes the horiz counter tree (ws is re-poisoned each iter);
// visibility to horiz is via the runtime's end-of-kernel writeback.
// ---------------------------------------------------------------------------
__global__ __launch_bounds__(256) void vert_g_kernel(const int* __restrict__ mask,
                                                     unsigned short* __restrict__ gbuf,
                                                     int* __restrict__ cnt0,
                                                     int* __restrict__ cnt1) {
    if (blockIdx.x == 0) {
        if (threadIdx.x < NLINES) cnt0[threadIdx.x * CNT_STRIDE] = 0;
        if (threadIdx.x == NLINES) *cnt1 = 0;
    }

    const int lane = threadIdx.x & 63;
    const int hc   = threadIdx.x >> 6;          // h-chunk 0..3
    const int blk  = blockIdx.x;                // 0..95
    const int wt   = blk & 3;
    const int b    = (blk >> 2) & 7;
    const int c_i  = blk >> 5;                  // 0..2
    const int cls  = c_i + 1;
    const int w    = (wt << 6) + lane;

    __shared__ int last_sh[4][64];              // highest bg row per chunk (or -512)
    __shared__ int first_sh[4][64];             // lowest bg row per chunk (or big)

    const int* mptr = mask + (b << 16) + (hc << 14) + w;   // row hc*64, col w
    int m[64];
    #pragma unroll
    for (int i = 0; i < 64; ++i) m[i] = mptr[i << 8];      // all independent
    unsigned long long bg = 0ull;
    #pragma unroll
    for (int i = 0; i < 64; ++i)
        bg |= (unsigned long long)(m[i] != cls) << i;

    last_sh[hc][lane]  = bg ? ((hc << 6) + 63 - __builtin_clzll(bg)) : -512;
    first_sh[hc][lane] = bg ? ((hc << 6) + __builtin_ctzll(bg)) : (1 << 20);
    __syncthreads();

    int carry_up = -512;                        // last bg row in chunks above
    #pragma unroll
    for (int k = 0; k < 4; ++k)
        if (k < hc) carry_up = max(carry_up, last_sh[k][lane]);
    int carry_dn = 1 << 20;                     // first bg row in chunks below
    #pragma unroll
    for (int k = 0; k < 4; ++k)
        if (k > hc) carry_dn = min(carry_dn, first_sh[k][lane]);

    unsigned short* gout = gbuf + (((c_i << 3) + b) << 16) + (hc << 14) + w;
    #pragma unroll 4
    for (int i = 0; i < 64; ++i) {
        int h = (hc << 6) + i;
        unsigned long long le = bg & (~0ull >> (63 - i));   // bg bits at rows <= h
        int last = le ? ((hc << 6) + 63 - __builtin_clzll(le)) : carry_up;
        int du = h - last;
        unsigned long long ge = bg >> i;                    // bg bits at rows >= h
        int first = ge ? (h + __builtin_ctzll(ge)) : carry_dn;
        int dd = first - h;
        int g = min(min(du, dd), 512);
        gout[i << 8] = (unsigned short)g;
    }
}

// ---------------------------------------------------------------------------
// Kernel 2: exact horizontal lower-envelope + fused loss partial + fused
// deterministic final reduction. 1536 blocks x 4 waves, ONE row per wave.
// Completion protocol (all relaxed agent-scope sc1 ops, zero cache
// maintenance): store acc[bid] -> s_waitcnt vmcnt(0) -> fetch_add on a
// TWO-LEVEL counter tree. Rationale: 1536 same-address RMWs serialize at
// the coherence point (~12 ns each ~= 18 us, measured last round); 64
// parallel line counters x 24 deep + one 64-deep master cuts the serial
// chain to ~1 us. Transitive visibility: each store drains before its line
// increment; line leader (old==23) implies its line's stores visible;
// master leader (old==63) implies all 1536 partials visible.
// Determinism: last block sums the 1536 partials in fixed index order.
// Exactness of the window search: D2[x] <= g2[x]; an x' improves only if
// |x-x'| <= g[x]-1 <= rowmax(g)-1 = R, so radius-R search is exact.
// ---------------------------------------------------------------------------
__global__ __launch_bounds__(256) void horiz_kernel(const unsigned short* __restrict__ gbuf,
                                                    const float* __restrict__ pred,
                                                    double* __restrict__ acc,
                                                    int* __restrict__ cnt0,
                                                    int* __restrict__ cnt1,
                                                    float* __restrict__ out) {
    const int lane = threadIdx.x & 63;
    const int wv   = threadIdx.x >> 6;
    const int row  = blockIdx.x * 4 + wv;       // 0..6143
    const int c_i  = row >> 11;
    const int b    = (row >> 8) & 7;
    const int h    = row & 255;
    const int cls  = c_i + 1;

    __shared__ __align__(16) int ext[4][512];   // per-wave padded g2 row: x = i-128
    __shared__ double wpart[4];
    __shared__ double fsum[4];
    __shared__ int lastflag;

    const int x0 = lane << 2;
    // issue both independent global loads immediately (overlapped latencies)
    const float* prow = pred + ((((b << 2) + cls) << 8) + h) * 256;
    float4 pv = *(const float4*)(prow + x0);
    ushort4 gv = *(const ushort4*)(gbuf + row * 256 + x0);

    int g0 = gv.x, g1 = gv.y, g2v = gv.z, g3 = gv.w;
    int q0 = g0 * g0, q1 = g1 * g1, q2 = g2v * g2v, q3 = g3 * g3;
    *(int4*)&ext[wv][128 + x0] = make_int4(q0, q1, q2, q3);
    // pads: [0,128) and [384,512)
    ext[wv][lane]       = BIGVAL;
    ext[wv][64 + lane]  = BIGVAL;
    ext[wv][384 + lane] = BIGVAL;
    ext[wv][448 + lane] = BIGVAL;
    // no barrier: single-wave ownership of ext[wv]; lgkmcnt orders ds ops

    // wave max of g -> window radius
    int gm = max(max(g0, g1), max(g2v, g3));
    #pragma unroll
    for (int off = 32; off > 0; off >>= 1) gm = max(gm, __shfl_xor(gm, off, 64));
    const int R = gm - 1;

    int D2[4] = { q0, q1, q2, q3 };
    const int* e = &ext[wv][128];

    if (R >= 120) {
        // brute force over all source columns (rare)
        for (int xp = 0; xp < 256; ++xp) {
            int s = e[xp];
            #pragma unroll
            for (int j = 0; j < 4; ++j) {
                int d = (x0 + j) - xp;
                int cand = s + d * d;
                D2[j] = (cand < D2[j]) ? cand : D2[j];
            }
        }
    } else if (R >= 1) {
        for (int o = 1; o <= R; ++o) {
            int oo = o * o;
            #pragma unroll
            for (int j = 0; j < 4; ++j) {
                int xj = x0 + j;
                int c1 = e[xj + o];
                int c2 = e[xj - o];
                int cm = (c1 < c2) ? c1 : c2;
                int cand = cm + oo;
                D2[j] = (cand < D2[j]) ? cand : D2[j];
            }
        }
    }
    // (R <= 0: all background in window -> D2 = g2)

    // loss terms: f32 sqrt (D2 < 2^24, exact in f32), fp64 accumulate
    double sum = (double)(sqrtf((float)D2[0]) * pv.x)
               + (double)(sqrtf((float)D2[1]) * pv.y)
               + (double)(sqrtf((float)D2[2]) * pv.z)
               + (double)(sqrtf((float)D2[3]) * pv.w);
    #pragma unroll
    for (int off = 32; off > 0; off >>= 1) sum += __shfl_xor(sum, off, 64);
    if (lane == 0) wpart[wv] = sum;
    __syncthreads();

    // block partial -> global (relaxed sc1), vmcnt drain, then two-level
    // relaxed counter RMW (low-contention, no cache maintenance).
    if (threadIdx.x == 0) {
        double bsum = (wpart[0] + wpart[1]) + (wpart[2] + wpart[3]);
        __hip_atomic_store(&acc[blockIdx.x], bsum, __ATOMIC_RELAXED,
                           __HIP_MEMORY_SCOPE_AGENT);
        asm volatile("s_waitcnt vmcnt(0)" ::: "memory");  // store at coherence point
        int flag = 0;
        int old0 = __hip_atomic_fetch_add(&cnt0[(blockIdx.x & (NLINES - 1)) * CNT_STRIDE],
                                          1, __ATOMIC_RELAXED, __HIP_MEMORY_SCOPE_AGENT);
        if (old0 == LINE_DEPTH - 1) {
            int old1 = __hip_atomic_fetch_add(cnt1, 1, __ATOMIC_RELAXED,
                                              __HIP_MEMORY_SCOPE_AGENT);
            flag = (old1 == NLINES - 1) ? 1 : 0;
        }
        lastflag = flag;
    }
    __syncthreads();
    if (!lastflag) return;

    // last block: deterministic final reduce over fixed index order.
    // Relaxed agent-scope loads read from the coherence point (cannot hit
    // stale L1/L2); all 1536 partials are there per the tree protocol.
    const int t = threadIdx.x;
    double s = 0.0;
    #pragma unroll
    for (int i = 0; i < NBLK / 256; ++i)
        s += __hip_atomic_load(&acc[t + i * 256], __ATOMIC_RELAXED,
                               __HIP_MEMORY_SCOPE_AGENT);
    #pragma unroll
    for (int off = 32; off > 0; off >>= 1) s += __shfl_xor(s, off, 64);
    if ((t & 63) == 0) fsum[t >> 6] = s;
    __syncthreads();
    if (t == 0) {
        double total = (fsum[0] + fsum[1]) + (fsum[2] + fsum[3]);
        double nd = sqrt(131072.0) + 1e-6;          // sqrt(H^2+W^2)+1e-6
        double norm = (double)(float)nd;            // ref casts to float32
        out[0] = (float)(total / norm / ((double)NCLS * (double)(B_ * H_ * W_)));
    }
}

extern "C" void kernel_launch(void* const* d_in, const int* in_sizes, int n_in,
                              void* d_out, int out_size, void* d_ws, size_t ws_size,
                              hipStream_t stream) {
    const float* pred = (const float*)d_in[0];   // [8,4,256,256] f32
    const int*   mask = (const int*)d_in[1];     // [8,256,256] int
    float* out = (float*)d_out;

    char* ws = (char*)d_ws;
    double* acc = (double*)ws;                                   // 1536 doubles
    int* cnt0 = (int*)(ws + 16384);                              // 64 x 128B counters
    int* cnt1 = (int*)(ws + 24576);                              // master counter
    unsigned short* gbuf = (unsigned short*)(ws + 65536);        // 3 MB

    vert_g_kernel<<<NCLS * 8 * 4, 256, 0, stream>>>(mask, gbuf, cnt0, cnt1);
    horiz_kernel<<<NROWS / 4, 256, 0, stream>>>(gbuf, pred, acc, cnt0, cnt1, out);
}

// Round 4
// 67.935 us; speedup vs baseline: 1.6396x; 1.0033x over previous
//
#include <hip/hip_runtime.h>
#include <math.h>

// Problem constants (fixed shapes from setup_inputs)
#define B_    8
#define C_    4
#define H_    256
#define W_    256
#define NCLS  3                      // classes 1..3
#define NROWS (NCLS * B_ * H_)       // 6144 rows for horizontal pass
#define NBLK  (NROWS / 8)            // 768 horiz blocks (8 rows/block, 2/wave)
#define NLINES 64                    // first-level counters (768 = 64 x 12)
#define LINE_DEPTH (NBLK / NLINES)   // 12 blocks per line
#define CNT_STRIDE 32                // ints between counters (128 B, own line)
#define BIGVAL (1 << 26)             // pad value, never wins the min

// ---------------------------------------------------------------------------
// Kernel 1: vertical 1D distance g = min(d_up, d_down, 512) via bitmask scan.
// Block = (class, b, w-tile of 64). 4 waves = 4 h-chunks of 64 rows.
// Thread (hc, lane): fully-unrolled 64 coalesced row loads into registers
// (max memory-level parallelism), builds u64 bg bitmask, then per row derives
// d_up via clz on prefix bits and d_down via ctz on suffix bits; cross-chunk
// carries via 4-entry LDS summaries. Matches ref semantics: no-bg-above =>
// d_up = h+512 (clamped 512); g = min(du, dd, BIG=512).
// Also zeroes the horiz counter tree (ws is re-poisoned each iter);
// visibility to horiz is via the runtime's end-of-kernel writeback.
// ---------------------------------------------------------------------------
__global__ __launch_bounds__(256) void vert_g_kernel(const int* __restrict__ mask,
                                                     unsigned short* __restrict__ gbuf,
                                                     int* __restrict__ cnt0,
                                                     int* __restrict__ cnt1) {
    if (blockIdx.x == 0) {
        if (threadIdx.x < NLINES) cnt0[threadIdx.x * CNT_STRIDE] = 0;
        if (threadIdx.x == NLINES) *cnt1 = 0;
    }

    const int lane = threadIdx.x & 63;
    const int hc   = threadIdx.x >> 6;          // h-chunk 0..3
    const int blk  = blockIdx.x;                // 0..95
    const int wt   = blk & 3;
    const int b    = (blk >> 2) & 7;
    const int c_i  = blk >> 5;                  // 0..2
    const int cls  = c_i + 1;
    const int w    = (wt << 6) + lane;

    __shared__ int last_sh[4][64];              // highest bg row per chunk (or -512)
    __shared__ int first_sh[4][64];             // lowest bg row per chunk (or big)

    const int* mptr = mask + (b << 16) + (hc << 14) + w;   // row hc*64, col w
    int m[64];
    #pragma unroll
    for (int i = 0; i < 64; ++i) m[i] = mptr[i << 8];      // all independent
    unsigned long long bg = 0ull;
    #pragma unroll
    for (int i = 0; i < 64; ++i)
        bg |= (unsigned long long)(m[i] != cls) << i;

    last_sh[hc][lane]  = bg ? ((hc << 6) + 63 - __builtin_clzll(bg)) : -512;
    first_sh[hc][lane] = bg ? ((hc << 6) + __builtin_ctzll(bg)) : (1 << 20);
    __syncthreads();

    int carry_up = -512;                        // last bg row in chunks above
    #pragma unroll
    for (int k = 0; k < 4; ++k)
        if (k < hc) carry_up = max(carry_up, last_sh[k][lane]);
    int carry_dn = 1 << 20;                     // first bg row in chunks below
    #pragma unroll
    for (int k = 0; k < 4; ++k)
        if (k > hc) carry_dn = min(carry_dn, first_sh[k][lane]);

    unsigned short* gout = gbuf + (((c_i << 3) + b) << 16) + (hc << 14) + w;
    #pragma unroll 4
    for (int i = 0; i < 64; ++i) {
        int h = (hc << 6) + i;
        unsigned long long le = bg & (~0ull >> (63 - i));   // bg bits at rows <= h
        int last = le ? ((hc << 6) + 63 - __builtin_clzll(le)) : carry_up;
        int du = h - last;
        unsigned long long ge = bg >> i;                    // bg bits at rows >= h
        int first = ge ? (h + __builtin_ctzll(ge)) : carry_dn;
        int dd = first - h;
        int g = min(min(du, dd), 512);
        gout[i << 8] = (unsigned short)g;
    }
}

// ---------------------------------------------------------------------------
// Kernel 2: exact horizontal lower-envelope + fused loss partial + fused
// deterministic final reduction. 768 blocks x 4 waves, TWO rows per wave
// (round-1 counters: latency-bound, VALUBusy 3.2%, HBM 1% -> double the
// in-flight loads per wave: 4 independent global loads issued up front).
// Completion protocol (all relaxed agent-scope sc1 ops, zero cache
// maintenance): store acc[bid] -> s_waitcnt vmcnt(0) -> fetch_add on a
// two-level counter tree (64 lines x 12 deep + 64-deep master); same-address
// RMWs at the coherence point serialize ~12ns each, so the tree keeps the
// serial chain ~1us (measured rounds 2->3: 83 -> 68us).
// Transitive visibility: each store drains before its line increment; line
// leader (old==11) implies its line's stores visible; master leader
// (old==63) implies all 768 partials visible.
// Determinism: last block sums the 768 partials in fixed index order.
// Exactness: D2[x] <= g2[x]; an x' improves only if |x-x'| <= g[x]-1 <=
// rowmax(g)-1 <= R (R = max over BOTH rows, an upper bound per row), so the
// radius-R search is exact; every candidate is a genuine upper bound.
// ---------------------------------------------------------------------------
__global__ __launch_bounds__(256) void horiz_kernel(const unsigned short* __restrict__ gbuf,
                                                    const float* __restrict__ pred,
                                                    double* __restrict__ acc,
                                                    int* __restrict__ cnt0,
                                                    int* __restrict__ cnt1,
                                                    float* __restrict__ out) {
    const int lane = threadIdx.x & 63;
    const int wv   = threadIdx.x >> 6;
    const int row0 = blockIdx.x * 8 + wv * 2;   // rows row0, row0+1 (same image:
                                                // 8 | 256 so no b/class crossing)
    const int c_i  = row0 >> 11;
    const int b    = (row0 >> 8) & 7;
    const int h0   = row0 & 255;
    const int cls  = c_i + 1;

    __shared__ __align__(16) int ext[8][512];   // per-row padded g2: x = i-128
    __shared__ double wpart[4];
    __shared__ double fsum[4];
    __shared__ int lastflag;

    const int x0 = lane << 2;
    // issue all 4 independent global loads immediately (overlapped latencies)
    const float* prow = pred + ((((b << 2) + cls) << 8) + h0) * 256;
    float4 pv0 = *(const float4*)(prow + x0);
    float4 pv1 = *(const float4*)(prow + 256 + x0);
    const unsigned short* grow = gbuf + row0 * 256;
    ushort4 gv0 = *(const ushort4*)(grow + x0);
    ushort4 gv1 = *(const ushort4*)(grow + 256 + x0);

    int* er0 = ext[wv * 2];
    int* er1 = ext[wv * 2 + 1];
    // pads: [0,128) and [384,512) (independent of loads, fill while in flight)
    er0[lane]       = BIGVAL; er1[lane]       = BIGVAL;
    er0[64 + lane]  = BIGVAL; er1[64 + lane]  = BIGVAL;
    er0[384 + lane] = BIGVAL; er1[384 + lane] = BIGVAL;
    er0[448 + lane] = BIGVAL; er1[448 + lane] = BIGVAL;

    int a0 = gv0.x, a1 = gv0.y, a2 = gv0.z, a3 = gv0.w;
    int b0 = gv1.x, b1 = gv1.y, b2 = gv1.z, b3 = gv1.w;
    int p0 = a0 * a0, p1 = a1 * a1, p2 = a2 * a2, p3 = a3 * a3;
    int s0 = b0 * b0, s1 = b1 * b1, s2 = b2 * b2, s3 = b3 * b3;
    *(int4*)&er0[128 + x0] = make_int4(p0, p1, p2, p3);
    *(int4*)&er1[128 + x0] = make_int4(s0, s1, s2, s3);
    // no barrier: single-wave ownership of its ext rows; lgkmcnt orders ds ops

    // wave max of g over BOTH rows -> shared window radius (upper bound/row)
    int gm = max(max(max(a0, a1), max(a2, a3)), max(max(b0, b1), max(b2, b3)));
    #pragma unroll
    for (int off = 32; off > 0; off >>= 1) gm = max(gm, __shfl_xor(gm, off, 64));
    const int R = gm - 1;

    int D0[4] = { p0, p1, p2, p3 };
    int D1[4] = { s0, s1, s2, s3 };
    const int* e0 = &er0[128];
    const int* e1 = &er1[128];

    if (R >= 120) {
        // brute force over all source columns (rare)
        for (int xp = 0; xp < 256; ++xp) {
            int t0 = e0[xp], t1 = e1[xp];
            #pragma unroll
            for (int j = 0; j < 4; ++j) {
                int d = (x0 + j) - xp;
                int dd = d * d;
                int c0 = t0 + dd, c1 = t1 + dd;
                D0[j] = (c0 < D0[j]) ? c0 : D0[j];
                D1[j] = (c1 < D1[j]) ? c1 : D1[j];
            }
        }
    } else if (R >= 1) {
        for (int o = 1; o <= R; ++o) {
            int oo = o * o;
            #pragma unroll
            for (int j = 0; j < 4; ++j) {
                int xj = x0 + j;
                int u0 = e0[xj + o], u1 = e0[xj - o];
                int v0 = e1[xj + o], v1 = e1[xj - o];
                int cu = ((u0 < u1) ? u0 : u1) + oo;
                int cv = ((v0 < v1) ? v0 : v1) + oo;
                D0[j] = (cu < D0[j]) ? cu : D0[j];
                D1[j] = (cv < D1[j]) ? cv : D1[j];
            }
        }
    }
    // (R <= 0: all background in window -> D = g2)

    // loss terms: f32 sqrt (D < 2^24, exact in f32), fp64 accumulate
    double sum = (double)(sqrtf((float)D0[0]) * pv0.x)
               + (double)(sqrtf((float)D0[1]) * pv0.y)
               + (double)(sqrtf((float)D0[2]) * pv0.z)
               + (double)(sqrtf((float)D0[3]) * pv0.w)
               + (double)(sqrtf((float)D1[0]) * pv1.x)
               + (double)(sqrtf((float)D1[1]) * pv1.y)
               + (double)(sqrtf((float)D1[2]) * pv1.z)
               + (double)(sqrtf((float)D1[3]) * pv1.w);
    #pragma unroll
    for (int off = 32; off > 0; off >>= 1) sum += __shfl_xor(sum, off, 64);
    if (lane == 0) wpart[wv] = sum;
    __syncthreads();

    // block partial -> global (relaxed sc1), vmcnt drain, then two-level
    // relaxed counter RMW (low-contention, no cache maintenance).
    if (threadIdx.x == 0) {
        double bsum = (wpart[0] + wpart[1]) + (wpart[2] + wpart[3]);
        __hip_atomic_store(&acc[blockIdx.x], bsum, __ATOMIC_RELAXED,
                           __HIP_MEMORY_SCOPE_AGENT);
        asm volatile("s_waitcnt vmcnt(0)" ::: "memory");  // store at coherence point
        int flag = 0;
        int old0 = __hip_atomic_fetch_add(&cnt0[(blockIdx.x & (NLINES - 1)) * CNT_STRIDE],
                                          1, __ATOMIC_RELAXED, __HIP_MEMORY_SCOPE_AGENT);
        if (old0 == LINE_DEPTH - 1) {
            int old1 = __hip_atomic_fetch_add(cnt1, 1, __ATOMIC_RELAXED,
                                              __HIP_MEMORY_SCOPE_AGENT);
            flag = (old1 == NLINES - 1) ? 1 : 0;
        }
        lastflag = flag;
    }
    __syncthreads();
    if (!lastflag) return;

    // last block: deterministic final reduce over fixed index order.
    // Relaxed agent-scope loads read from the coherence point (cannot hit
    // stale L1/L2); all 768 partials are there per the tree protocol.
    const int t = threadIdx.x;
    double s = 0.0;
    #pragma unroll
    for (int i = 0; i < NBLK / 256; ++i)
        s += __hip_atomic_load(&acc[t + i * 256], __ATOMIC_RELAXED,
                               __HIP_MEMORY_SCOPE_AGENT);
    #pragma unroll
    for (int off = 32; off > 0; off >>= 1) s += __shfl_xor(s, off, 64);
    if ((t & 63) == 0) fsum[t >> 6] = s;
    __syncthreads();
    if (t == 0) {
        double total = (fsum[0] + fsum[1]) + (fsum[2] + fsum[3]);
        double nd = sqrt(131072.0) + 1e-6;          // sqrt(H^2+W^2)+1e-6
        double norm = (double)(float)nd;            // ref casts to float32
        out[0] = (float)(total / norm / ((double)NCLS * (double)(B_ * H_ * W_)));
    }
}

extern "C" void kernel_launch(void* const* d_in, const int* in_sizes, int n_in,
                              void* d_out, int out_size, void* d_ws, size_t ws_size,
                              hipStream_t stream) {
    const float* pred = (const float*)d_in[0];   // [8,4,256,256] f32
    const int*   mask = (const int*)d_in[1];     // [8,256,256] int
    float* out = (float*)d_out;

    char* ws = (char*)d_ws;
    double* acc = (double*)ws;                                   // 768 doubles
    int* cnt0 = (int*)(ws + 16384);                              // 64 x 128B counters
    int* cnt1 = (int*)(ws + 24576);                              // master counter
    unsigned short* gbuf = (unsigned short*)(ws + 65536);        // 3 MB

    vert_g_kernel<<<NCLS * 8 * 4, 256, 0, stream>>>(mask, gbuf, cnt0, cnt1);
    horiz_kernel<<<NBLK, 256, 0, stream>>>(gbuf, pred, acc, cnt0, cnt1, out);
}